// Round 1
// baseline (653.468 us; speedup 1.0000x reference)
//
#include <hip/hip_runtime.h>
#include <cstddef>

#define B_ 4
#define N_ 1024
#define C_ 768
#define H_ 12
#define D_ 64

// ---------------- K1: QKV GEMM ----------------
// x[4096,768] @ W_qkv[768,2304] + b_qkv -> Q,K,V each [B,H,N,D]
__global__ __launch_bounds__(256) void k_qkv(const float* __restrict__ x,
                                             const float* __restrict__ W,
                                             const float* __restrict__ bias,
                                             float* __restrict__ Q,
                                             float* __restrict__ Kt,
                                             float* __restrict__ V) {
  __shared__ float As[16][64];  // [k][m]
  __shared__ float Bs[16][64];  // [k][n]
  const int tid = threadIdx.x;
  const int ty = tid >> 4, tx = tid & 15;
  const int row0 = blockIdx.y * 64;
  const int col0 = blockIdx.x * 64;
  const int ar = tid >> 2, akq = tid & 3;
  const int bkr = tid >> 4, bcq = tid & 15;
  float acc[4][4] = {};
  for (int k0 = 0; k0 < C_; k0 += 16) {
    float4 av = *reinterpret_cast<const float4*>(&x[(size_t)(row0 + ar) * C_ + k0 + akq * 4]);
    float4 bv = *reinterpret_cast<const float4*>(&W[(size_t)(k0 + bkr) * (3 * C_) + col0 + bcq * 4]);
    __syncthreads();
    As[akq * 4 + 0][ar] = av.x;
    As[akq * 4 + 1][ar] = av.y;
    As[akq * 4 + 2][ar] = av.z;
    As[akq * 4 + 3][ar] = av.w;
    *reinterpret_cast<float4*>(&Bs[bkr][bcq * 4]) = bv;
    __syncthreads();
#pragma unroll
    for (int k = 0; k < 16; ++k) {
      float4 a4 = *reinterpret_cast<const float4*>(&As[k][ty * 4]);
      float4 b4 = *reinterpret_cast<const float4*>(&Bs[k][tx * 4]);
      const float a[4] = {a4.x, a4.y, a4.z, a4.w};
      const float b[4] = {b4.x, b4.y, b4.z, b4.w};
#pragma unroll
      for (int i = 0; i < 4; ++i)
#pragma unroll
        for (int j = 0; j < 4; ++j) acc[i][j] += a[i] * b[j];
    }
  }
#pragma unroll
  for (int i = 0; i < 4; ++i) {
    const int row = row0 + ty * 4 + i;
    const int bb = row >> 10, n = row & 1023;
#pragma unroll
    for (int j = 0; j < 4; ++j) {
      const int col = col0 + tx * 4 + j;
      const float v = acc[i][j] + bias[col];
      const int t = col / C_;
      const int rem = col - t * C_;
      const int h = rem >> 6, dd = rem & 63;
      float* dst = (t == 0) ? Q : (t == 1) ? Kt : V;
      dst[(((size_t)bb * H_ + h) * N_ + n) * D_ + dd] = v;
    }
  }
}

// ---------------- K1b: per-row means of Q and K ----------------
__global__ __launch_bounds__(256) void k_means(const float* __restrict__ Q,
                                               const float* __restrict__ Kt,
                                               float* __restrict__ Qm,
                                               float* __restrict__ Km) {
  const int lane = threadIdx.x & 63;
  const int wave = threadIdx.x >> 6;
  const int row = blockIdx.x * 4 + wave;  // [0, B*H*N)
  const float* src = blockIdx.y ? Kt : Q;
  float v = src[(size_t)row * D_ + lane];
#pragma unroll
  for (int off = 32; off; off >>= 1) v += __shfl_down(v, off);
  if (lane == 0) (blockIdx.y ? Km : Qm)[row] = v * (1.0f / 64.0f);
}

// ---------------- K2: fused scores + channel mix -> logits ----------------
// logit[b,o,n,m] = sum_h Wc[o,h]*scale*(q_h.k_h) + Wc[o,H+h]*riem*((q_h.k_h)-64*qm*km)^2
// (b_conv skipped: constant over m -> softmax-invariant)
__global__ __launch_bounds__(256) void k_scores(const float* __restrict__ Q,
                                                const float* __restrict__ Kt,
                                                const float* __restrict__ Qm,
                                                const float* __restrict__ Km,
                                                const float* __restrict__ Wc,
                                                const float* __restrict__ scale_p,
                                                const float* __restrict__ riem_p,
                                                float* __restrict__ logits) {
  __shared__ float qs[32][68];
  __shared__ float ks[32][68];
  __shared__ float wcs[288];
  __shared__ float qms[32], kms[32];
  const int tid = threadIdx.x;
  const int b = blockIdx.z;
  const int n0 = blockIdx.y * 32;
  const int m0 = blockIdx.x * 32;
  const float scale = scale_p[0], riem = riem_p[0];
  for (int i = tid; i < 288; i += 256) wcs[i] = Wc[i];
  const int ty = tid >> 4, tx = tid & 15;
  const int ny0 = ty * 2, ny1 = ny0 + 1;
  const int mx0 = tx * 2, mx1 = mx0 + 1;
  const int lr = tid >> 3;            // 0..31 row for staging
  const int lc = (tid & 7) * 8;       // 8-float chunk
  float acc[12][4] = {};
  for (int h = 0; h < H_; ++h) {
    const float* qbase = &Q[(((size_t)b * H_ + h) * N_ + n0) * D_];
    const float* kbase = &Kt[(((size_t)b * H_ + h) * N_ + m0) * D_];
    float4 q0 = *reinterpret_cast<const float4*>(&qbase[lr * D_ + lc]);
    float4 q1 = *reinterpret_cast<const float4*>(&qbase[lr * D_ + lc + 4]);
    float4 kk0 = *reinterpret_cast<const float4*>(&kbase[lr * D_ + lc]);
    float4 kk1 = *reinterpret_cast<const float4*>(&kbase[lr * D_ + lc + 4]);
    __syncthreads();
    *reinterpret_cast<float4*>(&qs[lr][lc]) = q0;
    *reinterpret_cast<float4*>(&qs[lr][lc + 4]) = q1;
    *reinterpret_cast<float4*>(&ks[lr][lc]) = kk0;
    *reinterpret_cast<float4*>(&ks[lr][lc + 4]) = kk1;
    if (tid < 32) {
      qms[tid] = Qm[((size_t)b * H_ + h) * N_ + n0 + tid];
      kms[tid] = Km[((size_t)b * H_ + h) * N_ + m0 + tid];
    }
    __syncthreads();
    float s00 = 0, s01 = 0, s10 = 0, s11 = 0;
#pragma unroll
    for (int d = 0; d < D_; d += 4) {
      float4 qa = *reinterpret_cast<const float4*>(&qs[ny0][d]);
      float4 qb = *reinterpret_cast<const float4*>(&qs[ny1][d]);
      float4 ka = *reinterpret_cast<const float4*>(&ks[mx0][d]);
      float4 kb = *reinterpret_cast<const float4*>(&ks[mx1][d]);
      s00 += qa.x * ka.x + qa.y * ka.y + qa.z * ka.z + qa.w * ka.w;
      s01 += qa.x * kb.x + qa.y * kb.y + qa.z * kb.z + qa.w * kb.w;
      s10 += qb.x * ka.x + qb.y * ka.y + qb.z * ka.z + qb.w * ka.w;
      s11 += qb.x * kb.x + qb.y * kb.y + qb.z * kb.z + qb.w * kb.w;
    }
    const float qm0 = qms[ny0], qm1 = qms[ny1];
    const float km0 = kms[mx0], km1 = kms[mx1];
    const float u00 = s00 - 64.0f * qm0 * km0;
    const float u01 = s01 - 64.0f * qm0 * km1;
    const float u10 = s10 - 64.0f * qm1 * km0;
    const float u11 = s11 - 64.0f * qm1 * km1;
    const float a00 = s00 * scale, a01 = s01 * scale, a10 = s10 * scale, a11 = s11 * scale;
    const float r00 = u00 * u00 * riem, r01 = u01 * u01 * riem;
    const float r10 = u10 * u10 * riem, r11 = u11 * u11 * riem;
#pragma unroll
    for (int o = 0; o < H_; ++o) {
      const float we = wcs[o * 24 + h];
      const float wr = wcs[o * 24 + 12 + h];
      acc[o][0] += we * a00 + wr * r00;
      acc[o][1] += we * a01 + wr * r01;
      acc[o][2] += we * a10 + wr * r10;
      acc[o][3] += we * a11 + wr * r11;
    }
  }
#pragma unroll
  for (int o = 0; o < H_; ++o) {
    float* rowp = &logits[(((size_t)b * H_ + o) * N_ + n0) * N_ + m0];
    float2 w0 = {acc[o][0], acc[o][1]};
    float2 w1 = {acc[o][2], acc[o][3]};
    *reinterpret_cast<float2*>(&rowp[(size_t)ny0 * N_ + mx0]) = w0;
    *reinterpret_cast<float2*>(&rowp[(size_t)ny1 * N_ + mx0]) = w1;
  }
}

// ---------------- K3: in-place row softmax ----------------
__global__ __launch_bounds__(256) void k_softmax(float* __restrict__ attn) {
  __shared__ float red[4];
  __shared__ float red2[4];
  const size_t row = blockIdx.x;
  float* p = attn + row * N_;
  const int tid = threadIdx.x;
  float4 v = *reinterpret_cast<const float4*>(&p[tid * 4]);
  float mx = fmaxf(fmaxf(v.x, v.y), fmaxf(v.z, v.w));
#pragma unroll
  for (int off = 32; off; off >>= 1) mx = fmaxf(mx, __shfl_xor(mx, off));
  if ((tid & 63) == 0) red[tid >> 6] = mx;
  __syncthreads();
  mx = fmaxf(fmaxf(red[0], red[1]), fmaxf(red[2], red[3]));
  const float e0 = __expf(v.x - mx), e1 = __expf(v.y - mx);
  const float e2 = __expf(v.z - mx), e3 = __expf(v.w - mx);
  float s = e0 + e1 + e2 + e3;
#pragma unroll
  for (int off = 32; off; off >>= 1) s += __shfl_xor(s, off);
  if ((tid & 63) == 0) red2[tid >> 6] = s;
  __syncthreads();
  s = red2[0] + red2[1] + red2[2] + red2[3];
  const float inv = 1.0f / s;
  float4 o = {e0 * inv, e1 * inv, e2 * inv, e3 * inv};
  *reinterpret_cast<float4*>(&p[tid * 4]) = o;
}

// ---------------- K4: PV GEMM -> heads-merged [B,N,C] ----------------
__global__ __launch_bounds__(256) void k_pv(const float* __restrict__ attn,
                                            const float* __restrict__ V,
                                            float* __restrict__ outh) {
  __shared__ float As[32][64];  // [m][n]
  __shared__ float Bs[32][64];  // [m][d]
  const int tid = threadIdx.x;
  const int b = blockIdx.z, h = blockIdx.y;
  const int n0 = blockIdx.x * 64;
  const int ty = tid >> 4, tx = tid & 15;
  float acc[4][4] = {};
  const float* abase = attn + (((size_t)b * H_ + h) * N_ + n0) * N_;
  const float* vbase = V + ((size_t)b * H_ + h) * N_ * D_;
  for (int m0 = 0; m0 < N_; m0 += 32) {
    float4 av[2], vv[2];
#pragma unroll
    for (int t = 0; t < 2; ++t) {
      const int e = tid + t * 256;
      const int an = e >> 3, aq = e & 7;
      av[t] = *reinterpret_cast<const float4*>(&abase[(size_t)an * N_ + m0 + aq * 4]);
      const int vr = e >> 4, vc = e & 15;
      vv[t] = *reinterpret_cast<const float4*>(&vbase[(size_t)(m0 + vr) * D_ + vc * 4]);
    }
    __syncthreads();
#pragma unroll
    for (int t = 0; t < 2; ++t) {
      const int e = tid + t * 256;
      const int an = e >> 3, aq = e & 7;
      As[aq * 4 + 0][an] = av[t].x;
      As[aq * 4 + 1][an] = av[t].y;
      As[aq * 4 + 2][an] = av[t].z;
      As[aq * 4 + 3][an] = av[t].w;
      const int vr = e >> 4, vc = e & 15;
      *reinterpret_cast<float4*>(&Bs[vr][vc * 4]) = vv[t];
    }
    __syncthreads();
#pragma unroll
    for (int k = 0; k < 32; ++k) {
      float4 a4 = *reinterpret_cast<const float4*>(&As[k][ty * 4]);
      float4 b4 = *reinterpret_cast<const float4*>(&Bs[k][tx * 4]);
      const float a[4] = {a4.x, a4.y, a4.z, a4.w};
      const float bb[4] = {b4.x, b4.y, b4.z, b4.w};
#pragma unroll
      for (int i = 0; i < 4; ++i)
#pragma unroll
        for (int j = 0; j < 4; ++j) acc[i][j] += a[i] * bb[j];
    }
  }
#pragma unroll
  for (int i = 0; i < 4; ++i) {
    const int n = n0 + ty * 4 + i;
    float4 o = {acc[i][0], acc[i][1], acc[i][2], acc[i][3]};
    *reinterpret_cast<float4*>(&outh[((size_t)b * N_ + n) * C_ + h * D_ + tx * 4]) = o;
  }
}

// ---------------- K5: output projection ----------------
__global__ __launch_bounds__(256) void k_proj(const float* __restrict__ A,
                                              const float* __restrict__ W,
                                              const float* __restrict__ bias,
                                              float* __restrict__ out) {
  __shared__ float As[16][64];
  __shared__ float Bs[16][64];
  const int tid = threadIdx.x;
  const int ty = tid >> 4, tx = tid & 15;
  const int row0 = blockIdx.y * 64;
  const int col0 = blockIdx.x * 64;
  const int ar = tid >> 2, akq = tid & 3;
  const int bkr = tid >> 4, bcq = tid & 15;
  float acc[4][4] = {};
  for (int k0 = 0; k0 < C_; k0 += 16) {
    float4 av = *reinterpret_cast<const float4*>(&A[(size_t)(row0 + ar) * C_ + k0 + akq * 4]);
    float4 bv = *reinterpret_cast<const float4*>(&W[(size_t)(k0 + bkr) * C_ + col0 + bcq * 4]);
    __syncthreads();
    As[akq * 4 + 0][ar] = av.x;
    As[akq * 4 + 1][ar] = av.y;
    As[akq * 4 + 2][ar] = av.z;
    As[akq * 4 + 3][ar] = av.w;
    *reinterpret_cast<float4*>(&Bs[bkr][bcq * 4]) = bv;
    __syncthreads();
#pragma unroll
    for (int k = 0; k < 16; ++k) {
      float4 a4 = *reinterpret_cast<const float4*>(&As[k][ty * 4]);
      float4 b4 = *reinterpret_cast<const float4*>(&Bs[k][tx * 4]);
      const float a[4] = {a4.x, a4.y, a4.z, a4.w};
      const float b[4] = {b4.x, b4.y, b4.z, b4.w};
#pragma unroll
      for (int i = 0; i < 4; ++i)
#pragma unroll
        for (int j = 0; j < 4; ++j) acc[i][j] += a[i] * b[j];
    }
  }
  const float4 bv4 = *reinterpret_cast<const float4*>(&bias[col0 + tx * 4]);
#pragma unroll
  for (int i = 0; i < 4; ++i) {
    const int row = row0 + ty * 4 + i;
    float4 o = {acc[i][0] + bv4.x, acc[i][1] + bv4.y, acc[i][2] + bv4.z, acc[i][3] + bv4.w};
    *reinterpret_cast<float4*>(&out[(size_t)row * C_ + col0 + tx * 4]) = o;
  }
}

extern "C" void kernel_launch(void* const* d_in, const int* in_sizes, int n_in,
                              void* d_out, int out_size, void* d_ws, size_t ws_size,
                              hipStream_t stream) {
  (void)in_sizes; (void)n_in; (void)out_size; (void)ws_size;
  const float* x      = (const float*)d_in[0];
  const float* W_qkv  = (const float*)d_in[1];
  const float* b_qkv  = (const float*)d_in[2];
  const float* scale  = (const float*)d_in[3];
  const float* riem   = (const float*)d_in[4];
  const float* W_conv = (const float*)d_in[5];
  // d_in[6] = b_conv: constant along softmax axis -> no effect on outputs
  const float* W_proj = (const float*)d_in[7];
  const float* b_proj = (const float*)d_in[8];

  float* out_final = (float*)d_out;                         // [B,N,C]
  float* attn_out  = out_final + (size_t)B_ * N_ * C_;      // [B,H,N,N] (logits, then softmax in-place)

  const size_t qkv_elems = (size_t)B_ * H_ * N_ * D_;       // 3,145,728
  float* Q    = (float*)d_ws;
  float* Kt   = Q + qkv_elems;
  float* V    = Kt + qkv_elems;
  float* Qm   = V + qkv_elems;
  float* Km   = Qm + (size_t)B_ * H_ * N_;
  float* outh = Km + (size_t)B_ * H_ * N_;                  // [B,N,C]

  k_qkv<<<dim3(36, 64), 256, 0, stream>>>(x, W_qkv, b_qkv, Q, Kt, V);
  k_means<<<dim3((B_ * H_ * N_) / 4, 2), 256, 0, stream>>>(Q, Kt, Qm, Km);
  k_scores<<<dim3(N_ / 32, N_ / 32, B_), 256, 0, stream>>>(Q, Kt, Qm, Km, W_conv, scale, riem, attn_out);
  k_softmax<<<dim3(B_ * H_ * N_), 256, 0, stream>>>(attn_out);
  k_pv<<<dim3(N_ / 64, H_, B_), 256, 0, stream>>>(attn_out, V, outh);
  k_proj<<<dim3(C_ / 64, (B_ * N_) / 64), 256, 0, stream>>>(outh, W_proj, b_proj, out_final);
}

// Round 2
// 634.813 us; speedup vs baseline: 1.0294x; 1.0294x over previous
//
#include <hip/hip_runtime.h>
#include <cstddef>

#define B_ 4
#define N_ 1024
#define C_ 768
#define H_ 12
#define D_ 64

typedef __attribute__((ext_vector_type(8))) short bf16x8;
typedef __attribute__((ext_vector_type(4))) float f32x4;

__device__ __forceinline__ unsigned short f2bf(float f) {
  unsigned int u = __float_as_uint(f);
  u += 0x7fffu + ((u >> 16) & 1u);
  return (unsigned short)(u >> 16);
}
__device__ __forceinline__ float bf2f(unsigned short b) {
  return __uint_as_float(((unsigned int)b) << 16);
}

// ---------------- K1: QKV GEMM ----------------
// x[4096,768] @ W_qkv[768,2304] + b_qkv -> Qhi/Qlo, Khi/Klo (split bf16), V (f32)
__global__ __launch_bounds__(256) void k_qkv(const float* __restrict__ x,
                                             const float* __restrict__ W,
                                             const float* __restrict__ bias,
                                             short* __restrict__ Qhi,
                                             short* __restrict__ Qlo,
                                             short* __restrict__ Khi,
                                             short* __restrict__ Klo,
                                             float* __restrict__ V) {
  __shared__ float As[16][64];  // [k][m]
  __shared__ float Bs[16][64];  // [k][n]
  const int tid = threadIdx.x;
  const int ty = tid >> 4, tx = tid & 15;
  const int row0 = blockIdx.y * 64;
  const int col0 = blockIdx.x * 64;
  const int ar = tid >> 2, akq = tid & 3;
  const int bkr = tid >> 4, bcq = tid & 15;
  float acc[4][4] = {};
  for (int k0 = 0; k0 < C_; k0 += 16) {
    float4 av = *reinterpret_cast<const float4*>(&x[(size_t)(row0 + ar) * C_ + k0 + akq * 4]);
    float4 bv = *reinterpret_cast<const float4*>(&W[(size_t)(k0 + bkr) * (3 * C_) + col0 + bcq * 4]);
    __syncthreads();
    As[akq * 4 + 0][ar] = av.x;
    As[akq * 4 + 1][ar] = av.y;
    As[akq * 4 + 2][ar] = av.z;
    As[akq * 4 + 3][ar] = av.w;
    *reinterpret_cast<float4*>(&Bs[bkr][bcq * 4]) = bv;
    __syncthreads();
#pragma unroll
    for (int k = 0; k < 16; ++k) {
      float4 a4 = *reinterpret_cast<const float4*>(&As[k][ty * 4]);
      float4 b4 = *reinterpret_cast<const float4*>(&Bs[k][tx * 4]);
      const float a[4] = {a4.x, a4.y, a4.z, a4.w};
      const float b[4] = {b4.x, b4.y, b4.z, b4.w};
#pragma unroll
      for (int i = 0; i < 4; ++i)
#pragma unroll
        for (int j = 0; j < 4; ++j) acc[i][j] += a[i] * b[j];
    }
  }
#pragma unroll
  for (int i = 0; i < 4; ++i) {
    const int row = row0 + ty * 4 + i;
    const int bb = row >> 10, n = row & 1023;
#pragma unroll
    for (int j = 0; j < 4; ++j) {
      const int col = col0 + tx * 4 + j;
      const float v = acc[i][j] + bias[col];
      const int t = col / C_;
      const int rem = col - t * C_;
      const int h = rem >> 6, dd = rem & 63;
      const size_t idx = (((size_t)bb * H_ + h) * N_ + n) * D_ + dd;
      if (t == 2) {
        V[idx] = v;
      } else {
        const unsigned short hi = f2bf(v);
        const float fhi = bf2f(hi);
        const unsigned short lo = f2bf(v - fhi);
        if (t == 0) { Qhi[idx] = (short)hi; Qlo[idx] = (short)lo; }
        else        { Khi[idx] = (short)hi; Klo[idx] = (short)lo; }
      }
    }
  }
}

// ---------------- K1b: per-row means of Q and K (from hi+lo) ----------------
__global__ __launch_bounds__(256) void k_means(const short* __restrict__ Qhi,
                                               const short* __restrict__ Qlo,
                                               const short* __restrict__ Khi,
                                               const short* __restrict__ Klo,
                                               float* __restrict__ Qm,
                                               float* __restrict__ Km) {
  const int lane = threadIdx.x & 63;
  const int wave = threadIdx.x >> 6;
  const int row = blockIdx.x * 4 + wave;  // [0, B*H*N)
  const short* hi = blockIdx.y ? Khi : Qhi;
  const short* lo = blockIdx.y ? Klo : Qlo;
  float v = bf2f((unsigned short)hi[(size_t)row * D_ + lane]) +
            bf2f((unsigned short)lo[(size_t)row * D_ + lane]);
#pragma unroll
  for (int off = 32; off; off >>= 1) v += __shfl_down(v, off);
  if (lane == 0) (blockIdx.y ? Km : Qm)[row] = v * (1.0f / 64.0f);
}

// ---------------- K2: fused MFMA scores + channel mix -> logits ----------------
// s_h = q.k via split-bf16 MFMA (hi*hi + hi*lo + lo*hi); u = s - 64*qm*km;
// logit[o] = sum_h We[o,h]*scale*s + Wr[o,h]*riem*u^2   (b_conv softmax-invariant)
__global__ __launch_bounds__(256) void k_scores(
    const short* __restrict__ Qhi, const short* __restrict__ Qlo,
    const short* __restrict__ Khi, const short* __restrict__ Klo,
    const float* __restrict__ Qm, const float* __restrict__ Km,
    const float* __restrict__ Wc, const float* __restrict__ scale_p,
    const float* __restrict__ riem_p, float* __restrict__ logits) {
  const int tid = threadIdx.x;
  const int b = blockIdx.z;
  const int n0 = blockIdx.y * 32, m0 = blockIdx.x * 32;
  const int w = tid >> 6, l = tid & 63;
  const int nb = n0 + (w >> 1) * 16;   // wave's n-origin
  const int mb = m0 + (w & 1) * 16;    // wave's m-origin
  const int lr = l & 15, lg = l >> 4;
  const float scale = scale_p[0], riem = riem_p[0];
  f32x4 acc[12];
#pragma unroll
  for (int o = 0; o < 12; ++o) acc[o] = (f32x4){0.f, 0.f, 0.f, 0.f};

  for (int h = 0; h < H_; ++h) {
    // A-frag: Q[nb + (l&15)][ (l>>4)*8 + j + 32*t ]; B-frag: K[mb + (l&15)][same k]
    const size_t bq = (((size_t)b * H_ + h) * N_ + nb + lr) * D_ + lg * 8;
    const size_t bk = (((size_t)b * H_ + h) * N_ + mb + lr) * D_ + lg * 8;
    const bf16x8 qh0 = *reinterpret_cast<const bf16x8*>(Qhi + bq);
    const bf16x8 qh1 = *reinterpret_cast<const bf16x8*>(Qhi + bq + 32);
    const bf16x8 ql0 = *reinterpret_cast<const bf16x8*>(Qlo + bq);
    const bf16x8 ql1 = *reinterpret_cast<const bf16x8*>(Qlo + bq + 32);
    const bf16x8 kh0 = *reinterpret_cast<const bf16x8*>(Khi + bk);
    const bf16x8 kh1 = *reinterpret_cast<const bf16x8*>(Khi + bk + 32);
    const bf16x8 kl0 = *reinterpret_cast<const bf16x8*>(Klo + bk);
    const bf16x8 kl1 = *reinterpret_cast<const bf16x8*>(Klo + bk + 32);
    f32x4 s = {0.f, 0.f, 0.f, 0.f};
    s = __builtin_amdgcn_mfma_f32_16x16x32_bf16(qh0, kh0, s, 0, 0, 0);
    s = __builtin_amdgcn_mfma_f32_16x16x32_bf16(qh1, kh1, s, 0, 0, 0);
    s = __builtin_amdgcn_mfma_f32_16x16x32_bf16(qh0, kl0, s, 0, 0, 0);
    s = __builtin_amdgcn_mfma_f32_16x16x32_bf16(qh1, kl1, s, 0, 0, 0);
    s = __builtin_amdgcn_mfma_f32_16x16x32_bf16(ql0, kh0, s, 0, 0, 0);
    s = __builtin_amdgcn_mfma_f32_16x16x32_bf16(ql1, kh1, s, 0, 0, 0);

    // C/D layout: col = lane&15 (m), row = (lane>>4)*4 + reg (n)
    const float4 qm4 = *reinterpret_cast<const float4*>(&Qm[((size_t)b * H_ + h) * N_ + nb + lg * 4]);
    const float kmv = Km[((size_t)b * H_ + h) * N_ + mb + lr];
    const float qmv[4] = {qm4.x, qm4.y, qm4.z, qm4.w};
    float av[4], rv[4];
#pragma unroll
    for (int r = 0; r < 4; ++r) {
      const float sv = s[r];
      av[r] = sv * scale;
      const float u = fmaf(-64.0f * qmv[r], kmv, sv);
      rv[r] = u * u * riem;
    }
#pragma unroll
    for (int o = 0; o < 12; ++o) {
      const float we = Wc[o * 24 + h];
      const float wr = Wc[o * 24 + 12 + h];
#pragma unroll
      for (int r = 0; r < 4; ++r)
        acc[o][r] = fmaf(we, av[r], fmaf(wr, rv[r], acc[o][r]));
    }
  }
#pragma unroll
  for (int o = 0; o < 12; ++o) {
    float* dst = &logits[(((size_t)b * H_ + o) * N_ + nb) * N_ + mb + lr];
#pragma unroll
    for (int r = 0; r < 4; ++r)
      dst[(size_t)(lg * 4 + r) * N_] = acc[o][r];
  }
}

// ---------------- K3: in-place row softmax ----------------
__global__ __launch_bounds__(256) void k_softmax(float* __restrict__ attn) {
  __shared__ float red[4];
  __shared__ float red2[4];
  const size_t row = blockIdx.x;
  float* p = attn + row * N_;
  const int tid = threadIdx.x;
  float4 v = *reinterpret_cast<const float4*>(&p[tid * 4]);
  float mx = fmaxf(fmaxf(v.x, v.y), fmaxf(v.z, v.w));
#pragma unroll
  for (int off = 32; off; off >>= 1) mx = fmaxf(mx, __shfl_xor(mx, off));
  if ((tid & 63) == 0) red[tid >> 6] = mx;
  __syncthreads();
  mx = fmaxf(fmaxf(red[0], red[1]), fmaxf(red[2], red[3]));
  const float e0 = __expf(v.x - mx), e1 = __expf(v.y - mx);
  const float e2 = __expf(v.z - mx), e3 = __expf(v.w - mx);
  float s = e0 + e1 + e2 + e3;
#pragma unroll
  for (int off = 32; off; off >>= 1) s += __shfl_xor(s, off);
  if ((tid & 63) == 0) red2[tid >> 6] = s;
  __syncthreads();
  s = red2[0] + red2[1] + red2[2] + red2[3];
  const float inv = 1.0f / s;
  float4 o = {e0 * inv, e1 * inv, e2 * inv, e3 * inv};
  *reinterpret_cast<float4*>(&p[tid * 4]) = o;
}

// ---------------- K4: PV GEMM -> heads-merged [B,N,C] ----------------
__global__ __launch_bounds__(256) void k_pv(const float* __restrict__ attn,
                                            const float* __restrict__ V,
                                            float* __restrict__ outh) {
  __shared__ float As[32][64];  // [m][n]
  __shared__ float Bs[32][64];  // [m][d]
  const int tid = threadIdx.x;
  const int b = blockIdx.z, h = blockIdx.y;
  const int n0 = blockIdx.x * 64;
  const int ty = tid >> 4, tx = tid & 15;
  float acc[4][4] = {};
  const float* abase = attn + (((size_t)b * H_ + h) * N_ + n0) * N_;
  const float* vbase = V + ((size_t)b * H_ + h) * N_ * D_;
  for (int m0 = 0; m0 < N_; m0 += 32) {
    float4 av[2], vv[2];
#pragma unroll
    for (int t = 0; t < 2; ++t) {
      const int e = tid + t * 256;
      const int an = e >> 3, aq = e & 7;
      av[t] = *reinterpret_cast<const float4*>(&abase[(size_t)an * N_ + m0 + aq * 4]);
      const int vr = e >> 4, vc = e & 15;
      vv[t] = *reinterpret_cast<const float4*>(&vbase[(size_t)(m0 + vr) * D_ + vc * 4]);
    }
    __syncthreads();
#pragma unroll
    for (int t = 0; t < 2; ++t) {
      const int e = tid + t * 256;
      const int an = e >> 3, aq = e & 7;
      As[aq * 4 + 0][an] = av[t].x;
      As[aq * 4 + 1][an] = av[t].y;
      As[aq * 4 + 2][an] = av[t].z;
      As[aq * 4 + 3][an] = av[t].w;
      const int vr = e >> 4, vc = e & 15;
      *reinterpret_cast<float4*>(&Bs[vr][vc * 4]) = vv[t];
    }
    __syncthreads();
#pragma unroll
    for (int k = 0; k < 32; ++k) {
      float4 a4 = *reinterpret_cast<const float4*>(&As[k][ty * 4]);
      float4 b4 = *reinterpret_cast<const float4*>(&Bs[k][tx * 4]);
      const float a[4] = {a4.x, a4.y, a4.z, a4.w};
      const float bb[4] = {b4.x, b4.y, b4.z, b4.w};
#pragma unroll
      for (int i = 0; i < 4; ++i)
#pragma unroll
        for (int j = 0; j < 4; ++j) acc[i][j] += a[i] * bb[j];
    }
  }
#pragma unroll
  for (int i = 0; i < 4; ++i) {
    const int n = n0 + ty * 4 + i;
    float4 o = {acc[i][0], acc[i][1], acc[i][2], acc[i][3]};
    *reinterpret_cast<float4*>(&outh[((size_t)b * N_ + n) * C_ + h * D_ + tx * 4]) = o;
  }
}

// ---------------- K5: output projection ----------------
__global__ __launch_bounds__(256) void k_proj(const float* __restrict__ A,
                                              const float* __restrict__ W,
                                              const float* __restrict__ bias,
                                              float* __restrict__ out) {
  __shared__ float As[16][64];
  __shared__ float Bs[16][64];
  const int tid = threadIdx.x;
  const int ty = tid >> 4, tx = tid & 15;
  const int row0 = blockIdx.y * 64;
  const int col0 = blockIdx.x * 64;
  const int ar = tid >> 2, akq = tid & 3;
  const int bkr = tid >> 4, bcq = tid & 15;
  float acc[4][4] = {};
  for (int k0 = 0; k0 < C_; k0 += 16) {
    float4 av = *reinterpret_cast<const float4*>(&A[(size_t)(row0 + ar) * C_ + k0 + akq * 4]);
    float4 bv = *reinterpret_cast<const float4*>(&W[(size_t)(k0 + bkr) * C_ + col0 + bcq * 4]);
    __syncthreads();
    As[akq * 4 + 0][ar] = av.x;
    As[akq * 4 + 1][ar] = av.y;
    As[akq * 4 + 2][ar] = av.z;
    As[akq * 4 + 3][ar] = av.w;
    *reinterpret_cast<float4*>(&Bs[bkr][bcq * 4]) = bv;
    __syncthreads();
#pragma unroll
    for (int k = 0; k < 16; ++k) {
      float4 a4 = *reinterpret_cast<const float4*>(&As[k][ty * 4]);
      float4 b4 = *reinterpret_cast<const float4*>(&Bs[k][tx * 4]);
      const float a[4] = {a4.x, a4.y, a4.z, a4.w};
      const float b[4] = {b4.x, b4.y, b4.z, b4.w};
#pragma unroll
      for (int i = 0; i < 4; ++i)
#pragma unroll
        for (int j = 0; j < 4; ++j) acc[i][j] += a[i] * b[j];
    }
  }
  const float4 bv4 = *reinterpret_cast<const float4*>(&bias[col0 + tx * 4]);
#pragma unroll
  for (int i = 0; i < 4; ++i) {
    const int row = row0 + ty * 4 + i;
    float4 o = {acc[i][0] + bv4.x, acc[i][1] + bv4.y, acc[i][2] + bv4.z, acc[i][3] + bv4.w};
    *reinterpret_cast<float4*>(&out[(size_t)row * C_ + col0 + tx * 4]) = o;
  }
}

extern "C" void kernel_launch(void* const* d_in, const int* in_sizes, int n_in,
                              void* d_out, int out_size, void* d_ws, size_t ws_size,
                              hipStream_t stream) {
  (void)in_sizes; (void)n_in; (void)out_size; (void)ws_size;
  const float* x      = (const float*)d_in[0];
  const float* W_qkv  = (const float*)d_in[1];
  const float* b_qkv  = (const float*)d_in[2];
  const float* scale  = (const float*)d_in[3];
  const float* riem   = (const float*)d_in[4];
  const float* W_conv = (const float*)d_in[5];
  // d_in[6] = b_conv: constant along softmax axis -> no effect on outputs
  const float* W_proj = (const float*)d_in[7];
  const float* b_proj = (const float*)d_in[8];

  float* out_final = (float*)d_out;                         // [B,N,C]
  float* attn_out  = out_final + (size_t)B_ * N_ * C_;      // [B,H,N,N] (logits, then softmax in-place)

  const size_t qkv_elems = (size_t)B_ * H_ * N_ * D_;       // 3,145,728
  short* Qhi = (short*)d_ws;
  short* Qlo = Qhi + qkv_elems;
  short* Khi = Qlo + qkv_elems;
  short* Klo = Khi + qkv_elems;
  float* V   = (float*)(Klo + qkv_elems);
  float* Qm  = V + qkv_elems;
  float* Km  = Qm + (size_t)B_ * H_ * N_;
  float* outh = Km + (size_t)B_ * H_ * N_;                  // [B,N,C]

  k_qkv<<<dim3(36, 64), 256, 0, stream>>>(x, W_qkv, b_qkv, Qhi, Qlo, Khi, Klo, V);
  k_means<<<dim3((B_ * H_ * N_) / 4, 2), 256, 0, stream>>>(Qhi, Qlo, Khi, Klo, Qm, Km);
  k_scores<<<dim3(N_ / 32, N_ / 32, B_), 256, 0, stream>>>(Qhi, Qlo, Khi, Klo, Qm, Km, W_conv, scale, riem, attn_out);
  k_softmax<<<dim3(B_ * H_ * N_), 256, 0, stream>>>(attn_out);
  k_pv<<<dim3(N_ / 64, H_, B_), 256, 0, stream>>>(attn_out, V, outh);
  k_proj<<<dim3(C_ / 64, (B_ * N_) / 64), 256, 0, stream>>>(outh, W_proj, b_proj, out_final);
}

// Round 3
// 434.470 us; speedup vs baseline: 1.5041x; 1.4611x over previous
//
#include <hip/hip_runtime.h>
#include <cstddef>
#include <cstdint>

#define B_ 4
#define N_ 1024
#define C_ 768
#define H_ 12
#define D_ 64

typedef __attribute__((ext_vector_type(8))) short bf16x8;
typedef __attribute__((ext_vector_type(4))) short s16x4;
typedef __attribute__((ext_vector_type(4))) float f32x4;

#define MFMA16(a_, b_, c_) __builtin_amdgcn_mfma_f32_16x16x32_bf16((a_), (b_), (c_), 0, 0, 0)
#define GLLDS16(gp_, lp_) __builtin_amdgcn_global_load_lds( \
    (const __attribute__((address_space(1))) unsigned int*)(gp_), \
    (__attribute__((address_space(3))) unsigned int*)(lp_), 16, 0, 0)

__device__ __forceinline__ unsigned short f2bf(float f) {
  unsigned int u = __float_as_uint(f);
  u += 0x7fffu + ((u >> 16) & 1u);
  return (unsigned short)(u >> 16);
}
__device__ __forceinline__ float bf2f(unsigned short b) {
  return __uint_as_float(((unsigned int)b) << 16);
}

// ---------------- split x (elementwise, 8 elems/thread) ----------------
__global__ __launch_bounds__(256) void k_split_x(const float* __restrict__ x,
                                                 short* __restrict__ xhi,
                                                 short* __restrict__ xlo) {
  const size_t i = ((size_t)blockIdx.x * 256 + threadIdx.x) * 8;
  float4 a = *reinterpret_cast<const float4*>(&x[i]);
  float4 b = *reinterpret_cast<const float4*>(&x[i + 4]);
  float v[8] = {a.x, a.y, a.z, a.w, b.x, b.y, b.z, b.w};
  bf16x8 hi, lo;
#pragma unroll
  for (int j = 0; j < 8; ++j) {
    unsigned short h = f2bf(v[j]);
    hi[j] = (short)h;
    lo[j] = (short)f2bf(v[j] - bf2f(h));
  }
  *reinterpret_cast<bf16x8*>(&xhi[i]) = hi;
  *reinterpret_cast<bf16x8*>(&xlo[i]) = lo;
}

// ---------------- split + transpose weights: W[Kd][Nn] -> T[Nn][Kd] hi/lo ----------------
__global__ __launch_bounds__(256) void k_split_T(const float* __restrict__ W,
                                                 short* __restrict__ Thi,
                                                 short* __restrict__ Tlo,
                                                 int Kd, int Nn) {
  __shared__ float tile[32][33];
  const int k0 = blockIdx.y * 32, n0 = blockIdx.x * 32;
  const int t = threadIdx.x;
  const int r = t >> 3, cq = (t & 7) * 4;
  float4 v = *reinterpret_cast<const float4*>(&W[(size_t)(k0 + r) * Nn + n0 + cq]);
  tile[r][cq + 0] = v.x; tile[r][cq + 1] = v.y;
  tile[r][cq + 2] = v.z; tile[r][cq + 3] = v.w;
  __syncthreads();
  const int nrow = t >> 3, kq = (t & 7) * 4;
  s16x4 hi, lo;
#pragma unroll
  for (int i = 0; i < 4; ++i) {
    float f = tile[kq + i][nrow];
    unsigned short h = f2bf(f);
    hi[i] = (short)h;
    lo[i] = (short)f2bf(f - bf2f(h));
  }
  *reinterpret_cast<s16x4*>(&Thi[(size_t)(n0 + nrow) * Kd + k0 + kq]) = hi;
  *reinterpret_cast<s16x4*>(&Tlo[(size_t)(n0 + nrow) * Kd + k0 + kq]) = lo;
}

// ---------------- generic split-bf16 MFMA GEMM ----------------
// C[M][Nn] = A[M][Kd] * B^T (B stored [Nn][Kd]) + bias[n];  BM=128 BN=64 BK=32
__global__ __launch_bounds__(256) void k_gemm(const short* __restrict__ Ahi,
                                              const short* __restrict__ Alo,
                                              const short* __restrict__ Bhi,
                                              const short* __restrict__ Blo,
                                              const float* __restrict__ bias,
                                              float* __restrict__ Cout,
                                              int M, int Nn, int Kd) {
  __shared__ __align__(16) short sA[2][128 * 32];
  __shared__ __align__(16) short sB[2][64 * 32];
  const int tid = threadIdx.x;
  const int wv = tid >> 6, l = tid & 63;
  const int lr = l & 15, lg = l >> 4;
  const int row0 = blockIdx.y * 128;
  const int col0 = blockIdx.x * 64;
  const int wr = (wv >> 1) * 64;
  const int wc = (wv & 1) * 32;
  const int ar = tid >> 2, ac = tid & 3;
  f32x4 acc[4][2];
#pragma unroll
  for (int i = 0; i < 4; ++i)
#pragma unroll
    for (int j = 0; j < 2; ++j) acc[i][j] = (f32x4){0.f, 0.f, 0.f, 0.f};

  for (int k0 = 0; k0 < Kd; k0 += 32) {
    // stage A (2 rounds per hi/lo), B (1 round per hi/lo); pre-swizzled source chunks
#pragma unroll
    for (int j = 0; j < 2; ++j) {
      const int row = j * 64 + ar;
      const int cc = ac ^ ((row >> 1) & 3);
      const size_t so = (size_t)(row0 + row) * Kd + k0 + cc * 8;
      GLLDS16(Ahi + so, &sA[0][(j * 256 + (wv << 6)) * 8]);
      GLLDS16(Alo + so, &sA[1][(j * 256 + (wv << 6)) * 8]);
    }
    {
      const int row = ar;
      const int cc = ac ^ ((row >> 1) & 3);
      const size_t so = (size_t)(col0 + row) * Kd + k0 + cc * 8;
      GLLDS16(Bhi + so, &sB[0][(wv << 6) * 8]);
      GLLDS16(Blo + so, &sB[1][(wv << 6) * 8]);
    }
    __syncthreads();
    bf16x8 afh[4], afl[4], bfh[2], bfl[2];
#pragma unroll
    for (int ti = 0; ti < 4; ++ti) {
      const int row = wr + ti * 16 + lr;
      const int pc = lg ^ ((row >> 1) & 3);
      afh[ti] = *reinterpret_cast<const bf16x8*>(&sA[0][row * 32 + pc * 8]);
      afl[ti] = *reinterpret_cast<const bf16x8*>(&sA[1][row * 32 + pc * 8]);
    }
#pragma unroll
    for (int tj = 0; tj < 2; ++tj) {
      const int row = wc + tj * 16 + lr;
      const int pc = lg ^ ((row >> 1) & 3);
      bfh[tj] = *reinterpret_cast<const bf16x8*>(&sB[0][row * 32 + pc * 8]);
      bfl[tj] = *reinterpret_cast<const bf16x8*>(&sB[1][row * 32 + pc * 8]);
    }
#pragma unroll
    for (int ti = 0; ti < 4; ++ti)
#pragma unroll
      for (int tj = 0; tj < 2; ++tj) {
        acc[ti][tj] = MFMA16(afh[ti], bfh[tj], acc[ti][tj]);
        acc[ti][tj] = MFMA16(afl[ti], bfh[tj], acc[ti][tj]);
        acc[ti][tj] = MFMA16(afh[ti], bfl[tj], acc[ti][tj]);
      }
    __syncthreads();
  }
#pragma unroll
  for (int ti = 0; ti < 4; ++ti)
#pragma unroll
    for (int tj = 0; tj < 2; ++tj) {
      const int col = col0 + wc + tj * 16 + lr;
      const float bb = bias[col];
#pragma unroll
      for (int r = 0; r < 4; ++r) {
        const int row = row0 + wr + ti * 16 + lg * 4 + r;
        Cout[(size_t)row * Nn + col] = acc[ti][tj][r] + bb;
      }
    }
}

// ---------------- qkv post: split Q/K, transpose+split V, row means ----------------
__global__ __launch_bounds__(256) void k_qkv_post(const float* __restrict__ qkvf,
                                                  short* __restrict__ Qhi, short* __restrict__ Qlo,
                                                  short* __restrict__ Khi, short* __restrict__ Klo,
                                                  short* __restrict__ Vthi, short* __restrict__ Vtlo,
                                                  float* __restrict__ Qm, float* __restrict__ Km) {
  __shared__ unsigned short lvh[64][33];
  __shared__ unsigned short lvl[64][33];
  const int b = blockIdx.z, h = blockIdx.y, n0 = blockIdx.x * 32;
  const int t = threadIdx.x;
  const int row = t >> 3, d0 = (t & 7) * 8;
  const int n = n0 + row;
  const float* base = qkvf + ((size_t)(b * 1024 + n)) * 2304 + h * 64 + d0;
  const size_t qko = ((size_t)(b * H_ + h) * N_ + n) * D_ + d0;

#pragma unroll
  for (int part = 0; part < 2; ++part) {  // 0: q, 1: k
    float4 a = *reinterpret_cast<const float4*>(base + part * 768);
    float4 c = *reinterpret_cast<const float4*>(base + part * 768 + 4);
    float v[8] = {a.x, a.y, a.z, a.w, c.x, c.y, c.z, c.w};
    float s = v[0] + v[1] + v[2] + v[3] + v[4] + v[5] + v[6] + v[7];
#pragma unroll
    for (int off = 1; off < 8; off <<= 1) s += __shfl_xor(s, off);
    if ((t & 7) == 0) (part ? Km : Qm)[(size_t)(b * H_ + h) * N_ + n] = s * (1.0f / 64.0f);
    bf16x8 hi, lo;
#pragma unroll
    for (int j = 0; j < 8; ++j) {
      unsigned short hh = f2bf(v[j]);
      hi[j] = (short)hh;
      lo[j] = (short)f2bf(v[j] - bf2f(hh));
    }
    *reinterpret_cast<bf16x8*>((part ? Khi : Qhi) + qko) = hi;
    *reinterpret_cast<bf16x8*>((part ? Klo : Qlo) + qko) = lo;
  }
  {  // v -> transposed split
    float4 a = *reinterpret_cast<const float4*>(base + 1536);
    float4 c = *reinterpret_cast<const float4*>(base + 1536 + 4);
    float v[8] = {a.x, a.y, a.z, a.w, c.x, c.y, c.z, c.w};
#pragma unroll
    for (int j = 0; j < 8; ++j) {
      unsigned short hh = f2bf(v[j]);
      lvh[d0 + j][row] = hh;
      lvl[d0 + j][row] = f2bf(v[j] - bf2f(hh));
    }
  }
  __syncthreads();
  const int d = t >> 2, c = t & 3;
  bf16x8 vh, vl;
#pragma unroll
  for (int i = 0; i < 8; ++i) {
    vh[i] = (short)lvh[d][c * 8 + i];
    vl[i] = (short)lvl[d][c * 8 + i];
  }
  const size_t vo = ((size_t)(b * H_ + h) * D_ + d) * N_ + n0 + c * 8;
  *reinterpret_cast<bf16x8*>(Vthi + vo) = vh;
  *reinterpret_cast<bf16x8*>(Vtlo + vo) = vl;
}

// ---------------- scores + channel mix -> logits (+ partial softmax stats) ----------------
__global__ __launch_bounds__(256) void k_scores(
    const short* __restrict__ Qhi, const short* __restrict__ Qlo,
    const short* __restrict__ Khi, const short* __restrict__ Klo,
    const float* __restrict__ Qm, const float* __restrict__ Km,
    const float* __restrict__ Wc, const float* __restrict__ scale_p,
    const float* __restrict__ riem_p, float* __restrict__ logits,
    float2* __restrict__ stats) {
  __shared__ float2 sbuf[4][12][16];
  const int tid = threadIdx.x;
  const int b = blockIdx.z;
  const int n0 = blockIdx.y * 32, m0 = blockIdx.x * 32;
  const int w = tid >> 6, l = tid & 63;
  const int nb = n0 + (w >> 1) * 16;
  const int mb = m0 + (w & 1) * 16;
  const int lr = l & 15, lg = l >> 4;
  const float scale = scale_p[0], riem = riem_p[0];
  f32x4 acc[12];
#pragma unroll
  for (int o = 0; o < 12; ++o) acc[o] = (f32x4){0.f, 0.f, 0.f, 0.f};

  const size_t bq0 = (((size_t)b * H_) * N_ + nb + lr) * D_ + lg * 8;
  const size_t bk0 = (((size_t)b * H_) * N_ + mb + lr) * D_ + lg * 8;
  const size_t hstep = (size_t)N_ * D_;

  bf16x8 cq0 = *reinterpret_cast<const bf16x8*>(Qhi + bq0);
  bf16x8 cq1 = *reinterpret_cast<const bf16x8*>(Qhi + bq0 + 32);
  bf16x8 cl0 = *reinterpret_cast<const bf16x8*>(Qlo + bq0);
  bf16x8 cl1 = *reinterpret_cast<const bf16x8*>(Qlo + bq0 + 32);
  bf16x8 ck0 = *reinterpret_cast<const bf16x8*>(Khi + bk0);
  bf16x8 ck1 = *reinterpret_cast<const bf16x8*>(Khi + bk0 + 32);
  bf16x8 cm0 = *reinterpret_cast<const bf16x8*>(Klo + bk0);
  bf16x8 cm1 = *reinterpret_cast<const bf16x8*>(Klo + bk0 + 32);

  for (int h = 0; h < H_; ++h) {
    bf16x8 nq0, nq1, nl0, nl1, nk0, nk1, nm0, nm1;
    if (h < 11) {
      const size_t bq = bq0 + (h + 1) * hstep;
      const size_t bk = bk0 + (h + 1) * hstep;
      nq0 = *reinterpret_cast<const bf16x8*>(Qhi + bq);
      nq1 = *reinterpret_cast<const bf16x8*>(Qhi + bq + 32);
      nl0 = *reinterpret_cast<const bf16x8*>(Qlo + bq);
      nl1 = *reinterpret_cast<const bf16x8*>(Qlo + bq + 32);
      nk0 = *reinterpret_cast<const bf16x8*>(Khi + bk);
      nk1 = *reinterpret_cast<const bf16x8*>(Khi + bk + 32);
      nm0 = *reinterpret_cast<const bf16x8*>(Klo + bk);
      nm1 = *reinterpret_cast<const bf16x8*>(Klo + bk + 32);
    }
    f32x4 s = {0.f, 0.f, 0.f, 0.f};
    s = MFMA16(cq0, ck0, s);
    s = MFMA16(cq1, ck1, s);
    s = MFMA16(cq0, cm0, s);
    s = MFMA16(cq1, cm1, s);
    s = MFMA16(cl0, ck0, s);
    s = MFMA16(cl1, ck1, s);

    const float4 qm4 = *reinterpret_cast<const float4*>(&Qm[((size_t)b * H_ + h) * N_ + nb + lg * 4]);
    const float kmv = Km[((size_t)b * H_ + h) * N_ + mb + lr];
    const float qmv[4] = {qm4.x, qm4.y, qm4.z, qm4.w};
    float av[4], rv[4];
#pragma unroll
    for (int r = 0; r < 4; ++r) {
      const float sv = s[r];
      av[r] = sv * scale;
      const float u = fmaf(-64.0f * qmv[r], kmv, sv);
      rv[r] = u * u * riem;
    }
#pragma unroll
    for (int o = 0; o < 12; ++o) {
      const float we = Wc[o * 24 + h];
      const float wr = Wc[o * 24 + 12 + h];
#pragma unroll
      for (int r = 0; r < 4; ++r)
        acc[o][r] = fmaf(we, av[r], fmaf(wr, rv[r], acc[o][r]));
    }
    cq0 = nq0; cq1 = nq1; cl0 = nl0; cl1 = nl1;
    ck0 = nk0; ck1 = nk1; cm0 = nm0; cm1 = nm1;
  }
  // write logits
#pragma unroll
  for (int o = 0; o < 12; ++o) {
    float* dst = &logits[(((size_t)b * H_ + o) * N_ + nb) * N_ + mb + lr];
#pragma unroll
    for (int r = 0; r < 4; ++r)
      dst[(size_t)(lg * 4 + r) * N_] = acc[o][r];
  }
  // partial stats over this wave's 16 m, then merge wave pairs (32 m)
#pragma unroll
  for (int o = 0; o < 12; ++o) {
    float mx4[4], ss4[4];
#pragma unroll
    for (int r = 0; r < 4; ++r) {
      float mx = acc[o][r];
      mx = fmaxf(mx, __shfl_xor(mx, 1));
      mx = fmaxf(mx, __shfl_xor(mx, 2));
      mx = fmaxf(mx, __shfl_xor(mx, 4));
      mx = fmaxf(mx, __shfl_xor(mx, 8));
      float e = __expf(acc[o][r] - mx);
      e += __shfl_xor(e, 1);
      e += __shfl_xor(e, 2);
      e += __shfl_xor(e, 4);
      e += __shfl_xor(e, 8);
      mx4[r] = mx; ss4[r] = e;
    }
    if (lr < 4) sbuf[w][o][lg * 4 + lr] = make_float2(mx4[lr], ss4[lr]);
  }
  __syncthreads();
  if ((w & 1) == 0) {
    for (int i = l; i < 192; i += 64) {
      const int o = i >> 4, row = i & 15;
      const float2 p0 = sbuf[w][o][row];
      const float2 p1 = sbuf[w + 1][o][row];
      const float M = fmaxf(p0.x, p1.x);
      const float S = p0.y * __expf(p0.x - M) + p1.y * __expf(p1.x - M);
      const int n = n0 + (w >> 1) * 16 + row;
      stats[(((size_t)b * 12 + o) * 32 + blockIdx.x) * 1024 + n] = make_float2(M, S);
    }
  }
}

// ---------------- merge partial stats -> per-row (M, 1/S) ----------------
__global__ __launch_bounds__(256) void k_merge(const float2* __restrict__ stats,
                                               float2* __restrict__ merged) {
  const int bo = blockIdx.y;
  const int n = blockIdx.x * 256 + threadIdx.x;
  float M = -3.0e38f, S = 0.f;
  for (int seg = 0; seg < 32; ++seg) {
    const float2 p = stats[((size_t)bo * 32 + seg) * 1024 + n];
    if (p.x > M) {
      S = S * __expf(M - p.x) + p.y;
      M = p.x;
    } else {
      S += p.y * __expf(p.x - M);
    }
  }
  merged[(size_t)bo * 1024 + n] = make_float2(M, 1.0f / S);
}

// ---------------- fused softmax + attn-write + PV MFMA + split epilogue ----------------
__global__ __launch_bounds__(256) void k_pvsm(float* __restrict__ attn,
                                              const float2* __restrict__ merged,
                                              const short* __restrict__ Vthi,
                                              const short* __restrict__ Vtlo,
                                              short* __restrict__ ohi,
                                              short* __restrict__ olo) {
  __shared__ __align__(16) short sPhi[32 * 32];
  __shared__ __align__(16) short sPlo[32 * 32];
  __shared__ __align__(16) short sVhi[64 * 32];
  __shared__ __align__(16) short sVlo[64 * 32];
  __shared__ float sM[32], sIS[32];
  const int b = blockIdx.z, o = blockIdx.y;
  const int n0 = blockIdx.x * 32;
  const int bo = b * H_ + o;
  const int t = threadIdx.x;
  const int wv = t >> 6, l = t & 63;
  const int lr = l & 15, lg = l >> 4;
  const int nsub = (wv & 1) * 16, dsub = (wv >> 1) * 32;

  if (t < 32) {
    const float2 ms = merged[(size_t)bo * 1024 + n0 + t];
    sM[t] = ms.x;
    sIS[t] = ms.y;
  }
  __syncthreads();

  const int prow = t >> 3, pc4 = (t & 7) * 4;
  float* lrow = attn + ((size_t)bo * N_ + n0 + prow) * N_ + pc4;
  const int vd = t >> 2, vc = t & 3;
  const int vcc = vc ^ ((vd >> 1) & 3);
  const size_t vsrc0 = ((size_t)bo * D_ + vd) * N_ + vcc * 8;
  const int pchunk = (pc4 >> 3) ^ ((prow >> 1) & 3);
  const int pofs = prow * 32 + pchunk * 8 + (t & 1) * 4;

  f32x4 acc[2];
  acc[0] = (f32x4){0.f, 0.f, 0.f, 0.f};
  acc[1] = (f32x4){0.f, 0.f, 0.f, 0.f};

  for (int ms = 0; ms < 32; ++ms) {
    const int m0 = ms * 32;
    // stage Vt tiles (async)
    GLLDS16(Vthi + vsrc0 + m0, &sVhi[(wv << 6) * 8]);
    GLLDS16(Vtlo + vsrc0 + m0, &sVlo[(wv << 6) * 8]);
    // softmax + attn write (in-place)
    float4 lv = *reinterpret_cast<const float4*>(&lrow[m0]);
    const float Mr = sM[prow], iS = sIS[prow];
    float4 p;
    p.x = __expf(lv.x - Mr) * iS;
    p.y = __expf(lv.y - Mr) * iS;
    p.z = __expf(lv.z - Mr) * iS;
    p.w = __expf(lv.w - Mr) * iS;
    *reinterpret_cast<float4*>(&lrow[m0]) = p;
    const float pv[4] = {p.x, p.y, p.z, p.w};
    s16x4 phi, plo;
#pragma unroll
    for (int j = 0; j < 4; ++j) {
      unsigned short hh = f2bf(pv[j]);
      phi[j] = (short)hh;
      plo[j] = (short)f2bf(pv[j] - bf2f(hh));
    }
    *reinterpret_cast<s16x4*>(&sPhi[pofs]) = phi;
    *reinterpret_cast<s16x4*>(&sPlo[pofs]) = plo;
    __syncthreads();
    // PV MFMA
    const int arow = nsub + lr;
    const int apc = lg ^ ((arow >> 1) & 3);
    const bf16x8 pa = *reinterpret_cast<const bf16x8*>(&sPhi[arow * 32 + apc * 8]);
    const bf16x8 pb = *reinterpret_cast<const bf16x8*>(&sPlo[arow * 32 + apc * 8]);
#pragma unroll
    for (int dt = 0; dt < 2; ++dt) {
      const int drow = dsub + dt * 16 + lr;
      const int dpc = lg ^ ((drow >> 1) & 3);
      const bf16x8 vh = *reinterpret_cast<const bf16x8*>(&sVhi[drow * 32 + dpc * 8]);
      const bf16x8 vl = *reinterpret_cast<const bf16x8*>(&sVlo[drow * 32 + dpc * 8]);
      acc[dt] = MFMA16(pa, vh, acc[dt]);
      acc[dt] = MFMA16(pb, vh, acc[dt]);
      acc[dt] = MFMA16(pa, vl, acc[dt]);
    }
    __syncthreads();
  }
  // epilogue: split-write PV output as proj GEMM A operand [4096][768]
#pragma unroll
  for (int dt = 0; dt < 2; ++dt) {
    const int d = dsub + dt * 16 + lr;
#pragma unroll
    for (int r = 0; r < 4; ++r) {
      const int n = n0 + nsub + lg * 4 + r;
      const float val = acc[dt][r];
      const unsigned short hh = f2bf(val);
      const size_t oo = (size_t)(b * 1024 + n) * 768 + o * 64 + d;
      ohi[oo] = (short)hh;
      olo[oo] = (short)f2bf(val - bf2f(hh));
    }
  }
}

extern "C" void kernel_launch(void* const* d_in, const int* in_sizes, int n_in,
                              void* d_out, int out_size, void* d_ws, size_t ws_size,
                              hipStream_t stream) {
  (void)in_sizes; (void)n_in; (void)out_size; (void)ws_size;
  const float* x      = (const float*)d_in[0];
  const float* W_qkv  = (const float*)d_in[1];
  const float* b_qkv  = (const float*)d_in[2];
  const float* scale  = (const float*)d_in[3];
  const float* riem   = (const float*)d_in[4];
  const float* W_conv = (const float*)d_in[5];
  // d_in[6] = b_conv: constant along softmax axis -> softmax-invariant, skipped
  const float* W_proj = (const float*)d_in[7];
  const float* b_proj = (const float*)d_in[8];

  float* out_final = (float*)d_out;                     // [B,N,C]
  float* attn_out  = out_final + (size_t)B_ * N_ * C_;  // [B,H,N,N] logits -> attn in-place

  char* w = (char*)d_ws;
  short* xhi  = (short*)w;                       // 6291456 B
  short* xlo  = xhi + 3145728;                   // 6291456 B
  short* Wthi = (short*)(w + 12582912);          // 3538944 B
  short* Wtlo = Wthi + 1769472;                  // 3538944 B
  short* Wpthi = (short*)(w + 19660800);         // 1179648 B
  short* Wptlo = Wpthi + 589824;                 // 1179648 B
  float* qkvf = (float*)(w + 22020096);          // 37748736 B (reused: stats+merged)
  short* Qhi  = (short*)(w + 59768832);          // 6291456 B each x4
  short* Qlo  = Qhi + 3145728;
  short* Khi  = Qlo + 3145728;
  short* Klo  = Khi + 3145728;                   // ws end: 84934656 B
  // aliases (lifetime-disjoint)
  short* Vthi = xhi;                             // after k_gemm(qkv), x splits dead
  short* Vtlo = xlo;
  float* Qm = (float*)Wthi;                      // after k_gemm(qkv), Wt dead
  float* Km = Qm + 49152;
  float2* stats  = (float2*)qkvf;                // after k_qkv_post, qkvf dead
  float2* merged = stats + (size_t)48 * 32 * 1024;
  short* ohi = Qhi;                              // after k_scores, Q splits dead
  short* olo = Qlo;

  k_split_x<<<dim3(1536), 256, 0, stream>>>(x, xhi, xlo);
  k_split_T<<<dim3(72, 24), 256, 0, stream>>>(W_qkv, Wthi, Wtlo, 768, 2304);
  k_split_T<<<dim3(24, 24), 256, 0, stream>>>(W_proj, Wpthi, Wptlo, 768, 768);
  k_gemm<<<dim3(36, 32), 256, 0, stream>>>(xhi, xlo, Wthi, Wtlo, b_qkv, qkvf, 4096, 2304, 768);
  k_qkv_post<<<dim3(32, 12, 4), 256, 0, stream>>>(qkvf, Qhi, Qlo, Khi, Klo, Vthi, Vtlo, Qm, Km);
  k_scores<<<dim3(32, 32, 4), 256, 0, stream>>>(Qhi, Qlo, Khi, Klo, Qm, Km, W_conv, scale, riem, attn_out, stats);
  k_merge<<<dim3(4, 48), 256, 0, stream>>>(stats, merged);
  k_pvsm<<<dim3(32, 12, 4), 256, 0, stream>>>(attn_out, merged, Vthi, Vtlo, ohi, olo);
  k_gemm<<<dim3(12, 32), 256, 0, stream>>>(ohi, olo, Wpthi, Wptlo, b_proj, out_final, 4096, 768, 768);
}